// Round 9
// baseline (206.240 us; speedup 1.0000x reference)
//
#include <hip/hip_runtime.h>
#include <stdint.h>

#define D_MODEL 1024
#define NUM_HEADS 16
#define DK 64
#define SEQ 2048
#define BATCH 2
#define MROWS (BATCH * SEQ) /* 4096 */
#define LOG2E 1.4426950408889634f
#define FIXM 14.0f /* static softmax max, base-2 domain */

typedef short bf16x8 __attribute__((ext_vector_type(8)));
typedef float f32x4 __attribute__((ext_vector_type(4)));

__device__ __forceinline__ unsigned short f2bf(float f) { // RNE
    unsigned int u = __float_as_uint(f);
    u = (u + 0x7fffu + ((u >> 16) & 1u)) >> 16;
    return (unsigned short)u;
}
__device__ __forceinline__ unsigned short f2bf_trunc(float f) { // 1-op, P only
    return (unsigned short)(__float_as_uint(f) >> 16);
}
__device__ __forceinline__ float bf2f(unsigned short h) {
    return __uint_as_float(((unsigned int)h) << 16);
}
__device__ __forceinline__ void async16(const void* g, void* l) {
    __builtin_amdgcn_global_load_lds(
        (const __attribute__((address_space(1))) void*)g,
        (__attribute__((address_space(3))) void*)l, 16, 0, 0);
}
// 64-col bf16 tile: 8 16B-chunks/row; phys chunk p of row r holds logical p^(r&7)
#define SWZ64(row, b) ((((row) * 8) + ((b) ^ ((row) & 7))) * 8)

// ------------- merged cast fp32->bf16 + RoPE table fill -------------
// bx < 8192: cast. bx >= 8192 (64 blocks): RT[f][s] = (cos, sin) of s*invf(f).
__global__ void cast_all(const float4* __restrict__ X, const float4* __restrict__ Wq,
                         const float4* __restrict__ Wk, const float4* __restrict__ Wv,
                         const float4* __restrict__ Wo, ushort4* __restrict__ Xb,
                         ushort4* __restrict__ Wqkvb, ushort4* __restrict__ Wob,
                         float2* __restrict__ RT) {
    const int bx = blockIdx.x, t = threadIdx.x;
    if (bx < 8192) {
        int i = bx * 256 + t;
        const float4* src;
        ushort4* dst;
        int off;
        if (i < 1048576) { src = X; dst = Xb; off = i; }
        else if (i < 1310720) { src = Wq; dst = Wqkvb; off = i - 1048576; }
        else if (i < 1572864) { src = Wk; dst = Wqkvb + 262144; off = i - 1310720; }
        else if (i < 1835008) { src = Wv; dst = Wqkvb + 524288; off = i - 1572864; }
        else { src = Wo; dst = Wob; off = i - 1835008; }
        float4 v = src[off];
        ushort4 o;
        o.x = f2bf(v.x); o.y = f2bf(v.y); o.z = f2bf(v.z); o.w = f2bf(v.w);
        dst[off] = o;
    } else { // rope table: 16384 threads x 4 s-entries
        int idx = (bx - 8192) * 256 + t;
        int f = idx >> 9;            // 0..31
        int s4 = (idx & 511) * 4;    // 0..2044
        float invf = __expf(-(float)(2 * f) * (9.210340371976184f / 64.0f));
#pragma unroll
        for (int j = 0; j < 4; ++j) {
            int s = s4 + j;
            float sn, cs;
            __sincosf((float)s * invf, &sn, &cs);
            RT[f * SEQ + s] = make_float2(cs, sn);
        }
    }
}

// ---------------- QKV GEMM 128x128 BK=64 + fused RoPE / V-transpose --------
// C = X * Wqkv^T (M=4096, N=3072, K=1024). Q/K sections run MFMA with
// SWAPPED operands (D = C^T): lane holds 4 consecutive dk at fixed s ->
// rope partner is the adjacent register (no shfl), cos/sin from RT table,
// ushort4 stores to [bh][s][dk]. V section runs normal orientation: lane
// holds 4 consecutive s at fixed d -> ushort4 store to Vt [bh][d][s].
__global__ __launch_bounds__(256) void gemm_qkv_rope(
    const unsigned short* __restrict__ A, const unsigned short* __restrict__ B,
    const float2* __restrict__ RT, unsigned short* __restrict__ Qr,
    unsigned short* __restrict__ Kr, unsigned short* __restrict__ Vt) {
    __shared__ unsigned short As[128 * 64];
    __shared__ unsigned short Bs[128 * 64];
    const int K = D_MODEL;
    const int m0 = blockIdx.y * 128, n0 = blockIdx.x * 128;
    const int t = threadIdx.x;
    const int lane = t & 63, wave = t >> 6;
    const int mA = lane & 15, quad = lane >> 4;
    const int wr = (wave >> 1) * 64, wc = (wave & 1) * 64;
    const int sec = n0 >> 10; // block-uniform: 0=Q, 1=K, 2=V

    f32x4 acc[4][4] = {};
    for (int k0 = 0; k0 < K; k0 += 64) {
#pragma unroll
        for (int i = 0; i < 4; ++i) {
            int ch = i * 256 + t;
            int r = ch >> 3, b = (ch & 7) ^ (r & 7);
            async16(A + (size_t)(m0 + r) * K + k0 + b * 8, (char*)As + ch * 16);
            async16(B + (size_t)(n0 + r) * K + k0 + b * 8, (char*)Bs + ch * 16);
        }
        __syncthreads();
#pragma unroll
        for (int kk = 0; kk < 2; ++kk) {
            bf16x8 af[4], bfr[4];
#pragma unroll
            for (int mi = 0; mi < 4; ++mi) {
                int rr = wr + mi * 16 + mA;
                af[mi] = *(const bf16x8*)&As[SWZ64(rr, kk * 4 + quad)];
            }
#pragma unroll
            for (int ni = 0; ni < 4; ++ni) {
                int rr = wc + ni * 16 + mA;
                bfr[ni] = *(const bf16x8*)&Bs[SWZ64(rr, kk * 4 + quad)];
            }
            if (sec == 2) {
#pragma unroll
                for (int mi = 0; mi < 4; ++mi)
#pragma unroll
                    for (int ni = 0; ni < 4; ++ni)
                        acc[mi][ni] = __builtin_amdgcn_mfma_f32_16x16x32_bf16(
                            af[mi], bfr[ni], acc[mi][ni], 0, 0, 0);
            } else { // swapped: D = C^T
#pragma unroll
                for (int mi = 0; mi < 4; ++mi)
#pragma unroll
                    for (int ni = 0; ni < 4; ++ni)
                        acc[mi][ni] = __builtin_amdgcn_mfma_f32_16x16x32_bf16(
                            bfr[ni], af[mi], acc[mi][ni], 0, 0, 0);
            }
        }
        __syncthreads();
    }

    if (sec == 2) { // ---- V: direct transposed store (rows = 4 consecutive s)
#pragma unroll
        for (int mi = 0; mi < 4; ++mi)
#pragma unroll
            for (int ni = 0; ni < 4; ++ni) {
                int gm = m0 + wr + mi * 16 + quad * 4;
                int gn = n0 + wc + ni * 16 + mA;
                int d = gn & 1023, h = d >> 6, dk = d & 63;
                int b = gm >> 11, s = gm & 2047;
                ushort4 o;
                o.x = f2bf(acc[mi][ni][0]);
                o.y = f2bf(acc[mi][ni][1]);
                o.z = f2bf(acc[mi][ni][2]);
                o.w = f2bf(acc[mi][ni][3]);
                *(ushort4*)&Vt[((size_t)(b * NUM_HEADS + h) * DK + dk) * SEQ + s] = o;
            }
    } else { // ---- Q/K transposed acc: col = s (mA), regs = 4 consecutive dk
        unsigned short* Dst = (sec == 0) ? Qr : Kr;
#pragma unroll
        for (int mi = 0; mi < 4; ++mi) {
            int gm = m0 + wr + mi * 16 + mA;
            int b = gm >> 11, s = gm & 2047;
#pragma unroll
            for (int ni = 0; ni < 4; ++ni) {
                int gnb = n0 + wc + ni * 16 + quad * 4;
                int h = (gnb >> 6) & 15, dkb = gnb & 63;
                int f0 = dkb >> 1;
                float2 t0 = RT[f0 * SEQ + s];
                float2 t1 = RT[(f0 + 1) * SEQ + s];
                float a0 = acc[mi][ni][0], a1 = acc[mi][ni][1];
                float a2 = acc[mi][ni][2], a3 = acc[mi][ni][3];
                ushort4 o;
                o.x = f2bf(a0 * t0.x - a1 * t0.y);
                o.y = f2bf(a1 * t0.x + a0 * t0.y);
                o.z = f2bf(a2 * t1.x - a3 * t1.y);
                o.w = f2bf(a3 * t1.x + a2 * t1.y);
                *(ushort4*)&Dst[((size_t)(b * NUM_HEADS + h) * SEQ + s) * DK + dkb] = o;
            }
        }
    }
}

// ---------------- GEMM 128 x 64, BK=64: C = A * B^T (out-projection) -------
template <int TN, int OUT_BF16>
__global__ __launch_bounds__(256) void gemm_tile(
    const unsigned short* __restrict__ A, const unsigned short* __restrict__ B,
    void* __restrict__ Cout, int M, int N, int K) {
    __shared__ unsigned short As[128 * 64];
    __shared__ unsigned short Bs[TN * 64];
    const int m0 = blockIdx.y * 128, n0 = blockIdx.x * TN;
    const int t = threadIdx.x;
    const int lane = t & 63, wave = t >> 6;
    const int mA = lane & 15, quad = lane >> 4;
    constexpr int MI = (TN == 128) ? 4 : 2;
    constexpr int NI = 4;
    const int wr = (TN == 128) ? (wave >> 1) * 64 : wave * 32;
    const int wc = (TN == 128) ? (wave & 1) * 64 : 0;

    f32x4 acc[MI][NI] = {};
    for (int k0 = 0; k0 < K; k0 += 64) {
#pragma unroll
        for (int i = 0; i < 4; ++i) {
            int ch = i * 256 + t;
            int r = ch >> 3, b = (ch & 7) ^ (r & 7);
            async16(A + (size_t)(m0 + r) * K + k0 + b * 8, (char*)As + ch * 16);
        }
#pragma unroll
        for (int i = 0; i < TN / 32; ++i) {
            int ch = i * 256 + t;
            int r = ch >> 3, b = (ch & 7) ^ (r & 7);
            async16(B + (size_t)(n0 + r) * K + k0 + b * 8, (char*)Bs + ch * 16);
        }
        __syncthreads();
#pragma unroll
        for (int kk = 0; kk < 2; ++kk) {
            bf16x8 af[MI], bfr[NI];
#pragma unroll
            for (int mi = 0; mi < MI; ++mi) {
                int rr = wr + mi * 16 + mA;
                af[mi] = *(const bf16x8*)&As[SWZ64(rr, kk * 4 + quad)];
            }
#pragma unroll
            for (int ni = 0; ni < NI; ++ni) {
                int rr = wc + ni * 16 + mA;
                bfr[ni] = *(const bf16x8*)&Bs[SWZ64(rr, kk * 4 + quad)];
            }
#pragma unroll
            for (int mi = 0; mi < MI; ++mi)
#pragma unroll
                for (int ni = 0; ni < NI; ++ni)
                    acc[mi][ni] = __builtin_amdgcn_mfma_f32_16x16x32_bf16(
                        af[mi], bfr[ni], acc[mi][ni], 0, 0, 0);
        }
        __syncthreads();
    }
#pragma unroll
    for (int mi = 0; mi < MI; ++mi)
#pragma unroll
        for (int ni = 0; ni < NI; ++ni)
#pragma unroll
            for (int r = 0; r < 4; ++r) {
                int gm = m0 + wr + mi * 16 + quad * 4 + r;
                int gn = n0 + wc + ni * 16 + mA;
                if (OUT_BF16)
                    ((unsigned short*)Cout)[(size_t)gm * N + gn] = f2bf(acc[mi][ni][r]);
                else
                    ((float*)Cout)[(size_t)gm * N + gn] = acc[mi][ni][r];
            }
}

// ---------------- Flash attention v8: 32 q-rows per wave ----------------
// 256 thr / 4 waves; block = 128 q rows of one (b,h); wave w owns rows
// [w*32, w*32+32) (two 16-row MFMA tiles sharing one K/V fragment read ->
// LDS bytes per MFMA ~halved vs v6). KV 64-tiles staged via global_load_lds,
// double-buffered. Static-max softmax. Grid 512 flat, LPT (qt=15 first).
__global__ __launch_bounds__(256, 2) void flash_attn8(
    const unsigned short* __restrict__ Qr, const unsigned short* __restrict__ Kr,
    const unsigned short* __restrict__ Vt, unsigned short* __restrict__ Att) {
    __shared__ unsigned short Ks[2][64 * 64]; // 16 KB
    __shared__ unsigned short Vs[2][64 * 64]; // 16 KB
    __shared__ unsigned short Ps[4][32 * 64]; // 16 KB, XOR-swizzled rows
    const int id = blockIdx.x;
    const int bh = id & 31;
    const int qt = 15 - (id >> 5); // LPT: longest first
    const int t = threadIdx.x;
    const int lane = t & 63, wave = t >> 6;
    const int mA = lane & 15, quad = lane >> 4;
    const int qr0 = qt * 128 + wave * 32; // wave's 32 rows
    const int myTile = 2 * qt + (wave >> 1); // both 16-row tiles share this
    const int jtLast = 2 * qt + 1;
    const size_t qkbase = (size_t)bh * SEQ * DK;
    const unsigned short* Kg = Kr + qkbase;
    const unsigned short* Vg = Vt + (size_t)bh * DK * SEQ;

    // Q fragments (2 row-tiles), pre-scaled into base-2 softmax domain
    bf16x8 aq[2][2];
#pragma unroll
    for (int rt = 0; rt < 2; ++rt)
#pragma unroll
        for (int c = 0; c < 2; ++c) {
            bf16x8 raw = *(const bf16x8*)&Qr[qkbase + (size_t)(qr0 + rt * 16 + mA) * DK + c * 32 + quad * 8];
            bf16x8 s;
#pragma unroll
            for (int j = 0; j < 8; ++j)
                s[j] = (short)f2bf(bf2f((unsigned short)raw[j]) * (0.125f * LOG2E));
            aq[rt][c] = s;
        }

    f32x4 accT[2][4] = {}; // O^T per row-tile
    float lsum[2][4] = {};
    unsigned short* Pw = Ps[wave];

    // stage tile 0 into buffer 0
#pragma unroll
    for (int i = 0; i < 2; ++i) {
        int ch = i * 256 + t;
        int row = ch >> 3, sb = (ch & 7) ^ (row & 7);
        async16(Kg + (size_t)row * DK + sb * 8, (char*)Ks[0] + ch * 16);
        async16(Vg + (size_t)row * SEQ + sb * 8, (char*)Vs[0] + ch * 16);
    }

    for (int jt = 0; jt <= jtLast; ++jt) {
        __syncthreads(); // stage(jt) visible; compute(jt-1) done
        const int cur = jt & 1;
        if (jt < jtLast) { // prefetch next tile (overlaps compute)
            const int j1 = (jt + 1) * 64;
#pragma unroll
            for (int i = 0; i < 2; ++i) {
                int ch = i * 256 + t;
                int row = ch >> 3, sb = (ch & 7) ^ (row & 7);
                async16(Kg + (size_t)(j1 + row) * DK + sb * 8, (char*)Ks[cur ^ 1] + ch * 16);
                async16(Vg + (size_t)row * SEQ + j1 + sb * 8, (char*)Vs[cur ^ 1] + ch * 16);
            }
        }
        if (jt > myTile) continue; // wave-uniform; barrier alignment kept

        const int j0 = jt * 64;
        const unsigned short* Kt = Ks[cur];
        const unsigned short* Vtile = Vs[cur];

        // ---- K fragments once, reused by both row-tiles ----
        bf16x8 kf[4][2];
#pragma unroll
        for (int js = 0; js < 4; ++js)
#pragma unroll
            for (int c = 0; c < 2; ++c)
                kf[js][c] = *(const bf16x8*)&Kt[SWZ64(js * 16 + mA, c * 4 + quad)];

        f32x4 sc[2][4] = {};
#pragma unroll
        for (int rt = 0; rt < 2; ++rt)
#pragma unroll
            for (int js = 0; js < 4; ++js) {
                sc[rt][js] = __builtin_amdgcn_mfma_f32_16x16x32_bf16(
                    aq[rt][0], kf[js][0], sc[rt][js], 0, 0, 0);
                sc[rt][js] = __builtin_amdgcn_mfma_f32_16x16x32_bf16(
                    aq[rt][1], kf[js][1], sc[rt][js], 0, 0, 0);
            }
        if (jt == myTile) { // diagonal causal mask (both row-tiles)
#pragma unroll
            for (int rt = 0; rt < 2; ++rt)
#pragma unroll
                for (int js = 0; js < 4; ++js) {
                    int gcol = j0 + js * 16 + mA;
#pragma unroll
                    for (int r = 0; r < 4; ++r)
                        if (gcol > qr0 + rt * 16 + quad * 4 + r) sc[rt][js][r] = -1e30f;
                }
        }

        // ---- p = exp2(s - FIXM); P rows rt*16 + quad*4 + r ----
#pragma unroll
        for (int rt = 0; rt < 2; ++rt)
#pragma unroll
            for (int js = 0; js < 4; ++js)
#pragma unroll
                for (int r = 0; r < 4; ++r) {
                    float p = __builtin_amdgcn_exp2f(sc[rt][js][r] - FIXM);
                    lsum[rt][r] += p;
                    int q = rt * 16 + quad * 4 + r;
                    Pw[SWZ64(q, js * 2 + (mA >> 3)) + (mA & 7)] = f2bf_trunc(p);
                }

        // ---- V fragments once, PV for both row-tiles ----
        bf16x8 vf[4][2];
#pragma unroll
        for (int tn = 0; tn < 4; ++tn)
#pragma unroll
            for (int c = 0; c < 2; ++c)
                vf[tn][c] = *(const bf16x8*)&Vtile[SWZ64(tn * 16 + mA, c * 4 + quad)];
#pragma unroll
        for (int rt = 0; rt < 2; ++rt) {
            bf16x8 ap0 = *(const bf16x8*)&Pw[SWZ64(rt * 16 + mA, quad)];
            bf16x8 ap1 = *(const bf16x8*)&Pw[SWZ64(rt * 16 + mA, quad + 4)];
#pragma unroll
            for (int tn = 0; tn < 4; ++tn) { // A=V, B=P -> O^T
                accT[rt][tn] = __builtin_amdgcn_mfma_f32_16x16x32_bf16(
                    vf[tn][0], ap0, accT[rt][tn], 0, 0, 0);
                accT[rt][tn] = __builtin_amdgcn_mfma_f32_16x16x32_bf16(
                    vf[tn][1], ap1, accT[rt][tn], 0, 0, 0);
            }
        }
    }

    // ---- epilogue: in-register row-sum reduce + broadcast ----
    const int b = bh >> 4, h = bh & 15;
#pragma unroll
    for (int rt = 0; rt < 2; ++rt) {
#pragma unroll
        for (int r = 0; r < 4; ++r)
#pragma unroll
            for (int off = 1; off < 16; off <<= 1)
                lsum[rt][r] += __shfl_xor(lsum[rt][r], off, 64);
        const int srcl = (mA >> 2) << 4;
        float s0 = __shfl(lsum[rt][0], srcl), s1 = __shfl(lsum[rt][1], srcl);
        float s2 = __shfl(lsum[rt][2], srcl), s3 = __shfl(lsum[rt][3], srcl);
        const int rr = mA & 3;
        float sum = (rr == 0) ? s0 : (rr == 1) ? s1 : (rr == 2) ? s2 : s3;
        const float rl = 1.0f / sum;
        const int q = qr0 + rt * 16 + mA;
#pragma unroll
        for (int tn = 0; tn < 4; ++tn) {
            ushort4 o;
            o.x = f2bf(accT[rt][tn][0] * rl);
            o.y = f2bf(accT[rt][tn][1] * rl);
            o.z = f2bf(accT[rt][tn][2] * rl);
            o.w = f2bf(accT[rt][tn][3] * rl);
            *(ushort4*)&Att[(size_t)(b * SEQ + q) * D_MODEL + h * DK + tn * 16 + quad * 4] = o;
        }
    }
}

extern "C" void kernel_launch(void* const* d_in, const int* in_sizes, int n_in,
                              void* d_out, int out_size, void* d_ws, size_t ws_size,
                              hipStream_t stream) {
    const float* X = (const float*)d_in[0];
    const float* Wq = (const float*)d_in[1];
    const float* Wk = (const float*)d_in[2];
    const float* Wv = (const float*)d_in[3];
    const float* Wo = (const float*)d_in[4];

    char* ws = (char*)d_ws;
    // layout (MiB): Xb 0-8 | Wqkvb 8-14 | Wob 14-16 | Qr 16-24 | Kr 24-32 |
    //               Vt 32-40 | Att 40-48 | RT 48-48.5
    unsigned short* Xb    = (unsigned short*)(ws + 0);
    unsigned short* Wqkvb = (unsigned short*)(ws + (8u << 20));
    unsigned short* Wob   = (unsigned short*)(ws + (14u << 20));
    unsigned short* Qr    = (unsigned short*)(ws + (16u << 20));
    unsigned short* Kr    = (unsigned short*)(ws + (24u << 20));
    unsigned short* Vt    = (unsigned short*)(ws + (32u << 20));
    unsigned short* Att   = (unsigned short*)(ws + (40u << 20));
    float2*         RT    = (float2*)(ws + (48u << 20));

    cast_all<<<8192 + 64, 256, 0, stream>>>((const float4*)X, (const float4*)Wq,
                                            (const float4*)Wk, (const float4*)Wv,
                                            (const float4*)Wo, (ushort4*)Xb,
                                            (ushort4*)Wqkvb, (ushort4*)Wob, RT);

    // fused QKV projection + RoPE (table) + V-transpose
    gemm_qkv_rope<<<dim3(3072 / 128, MROWS / 128), 256, 0, stream>>>(
        Xb, Wqkvb, RT, Qr, Kr, Vt);

    flash_attn8<<<512, 256, 0, stream>>>(Qr, Kr, Vt, Att);

    // output projection (fp32 out), 128x64 tiles for 2 blocks/CU
    gemm_tile<64, 0><<<dim3(D_MODEL / 64, MROWS / 128), 256, 0, stream>>>(
        Att, Wob, d_out, MROWS, D_MODEL, D_MODEL);
}

// Round 10
// 188.390 us; speedup vs baseline: 1.0947x; 1.0947x over previous
//
#include <hip/hip_runtime.h>
#include <stdint.h>

#define D_MODEL 1024
#define NUM_HEADS 16
#define DK 64
#define SEQ 2048
#define BATCH 2
#define MROWS (BATCH * SEQ) /* 4096 */
#define LOG2E 1.4426950408889634f
#define FIXM 14.0f /* static softmax max, base-2 domain */

typedef short bf16x8 __attribute__((ext_vector_type(8)));
typedef float f32x4 __attribute__((ext_vector_type(4)));

__device__ __forceinline__ unsigned short f2bf(float f) { // RNE
    unsigned int u = __float_as_uint(f);
    u = (u + 0x7fffu + ((u >> 16) & 1u)) >> 16;
    return (unsigned short)u;
}
__device__ __forceinline__ unsigned short f2bf_trunc(float f) { // 1-op, P only
    return (unsigned short)(__float_as_uint(f) >> 16);
}
__device__ __forceinline__ float bf2f(unsigned short h) {
    return __uint_as_float(((unsigned int)h) << 16);
}
__device__ __forceinline__ void async16(const void* g, void* l) {
    __builtin_amdgcn_global_load_lds(
        (const __attribute__((address_space(1))) void*)g,
        (__attribute__((address_space(3))) void*)l, 16, 0, 0);
}
// 64-col bf16 tile: 8 16B-chunks/row; phys chunk p of row r holds logical p^(r&7)
#define SWZ64(row, b) ((((row) * 8) + ((b) ^ ((row) & 7))) * 8)

// ------------- merged cast fp32->bf16 + RoPE table fill -------------
__global__ void cast_all(const float4* __restrict__ X, const float4* __restrict__ Wq,
                         const float4* __restrict__ Wk, const float4* __restrict__ Wv,
                         const float4* __restrict__ Wo, ushort4* __restrict__ Xb,
                         ushort4* __restrict__ Wqkvb, ushort4* __restrict__ Wob,
                         float2* __restrict__ RT) {
    const int bx = blockIdx.x, t = threadIdx.x;
    if (bx < 8192) {
        int i = bx * 256 + t;
        const float4* src;
        ushort4* dst;
        int off;
        if (i < 1048576) { src = X; dst = Xb; off = i; }
        else if (i < 1310720) { src = Wq; dst = Wqkvb; off = i - 1048576; }
        else if (i < 1572864) { src = Wk; dst = Wqkvb + 262144; off = i - 1310720; }
        else if (i < 1835008) { src = Wv; dst = Wqkvb + 524288; off = i - 1572864; }
        else { src = Wo; dst = Wob; off = i - 1835008; }
        float4 v = src[off];
        ushort4 o;
        o.x = f2bf(v.x); o.y = f2bf(v.y); o.z = f2bf(v.z); o.w = f2bf(v.w);
        dst[off] = o;
    } else { // rope table: 16384 threads x 4 s-entries
        int idx = (bx - 8192) * 256 + t;
        int f = idx >> 9;
        int s4 = (idx & 511) * 4;
        float invf = __expf(-(float)(2 * f) * (9.210340371976184f / 64.0f));
#pragma unroll
        for (int j = 0; j < 4; ++j) {
            int s = s4 + j;
            float sn, cs;
            __sincosf((float)s * invf, &sn, &cs);
            RT[f * SEQ + s] = make_float2(cs, sn);
        }
    }
}

// ---------------- QKV GEMM 128x128 BK=64, templated epilogue ----------------
// C = X * Wqkv^T. SWAP=1 (Q/K sections, n0 in [0,2048)): MFMA with swapped
// operands (D=C^T) -> lane holds 4 consecutive dk at fixed s; rope via RT
// table on fp32 acc; ushort4 stores to Qr/Kr [bh][s][dk]. SWAP=0 (V section,
// n0 in [2048,3072)): normal orientation -> lane holds 4 consecutive s at
// fixed d; ushort4 store to Vt [bh][d][s]. No runtime branch in the K-loop.
template <int SWAP>
__global__ __launch_bounds__(256) void gemm_qkv(
    const unsigned short* __restrict__ A, const unsigned short* __restrict__ B,
    const float2* __restrict__ RT, unsigned short* __restrict__ Qr,
    unsigned short* __restrict__ Kr, unsigned short* __restrict__ Vt,
    int n_base) {
    __shared__ unsigned short As[128 * 64];
    __shared__ unsigned short Bs[128 * 64];
    const int K = D_MODEL;
    const int m0 = blockIdx.y * 128, n0 = n_base + blockIdx.x * 128;
    const int t = threadIdx.x;
    const int lane = t & 63, wave = t >> 6;
    const int mA = lane & 15, quad = lane >> 4;
    const int wr = (wave >> 1) * 64, wc = (wave & 1) * 64;

    f32x4 acc[4][4] = {};
    for (int k0 = 0; k0 < K; k0 += 64) {
#pragma unroll
        for (int i = 0; i < 4; ++i) {
            int ch = i * 256 + t;
            int r = ch >> 3, b = (ch & 7) ^ (r & 7);
            async16(A + (size_t)(m0 + r) * K + k0 + b * 8, (char*)As + ch * 16);
            async16(B + (size_t)(n0 + r) * K + k0 + b * 8, (char*)Bs + ch * 16);
        }
        __syncthreads();
#pragma unroll
        for (int kk = 0; kk < 2; ++kk) {
            bf16x8 af[4], bfr[4];
#pragma unroll
            for (int mi = 0; mi < 4; ++mi) {
                int rr = wr + mi * 16 + mA;
                af[mi] = *(const bf16x8*)&As[SWZ64(rr, kk * 4 + quad)];
            }
#pragma unroll
            for (int ni = 0; ni < 4; ++ni) {
                int rr = wc + ni * 16 + mA;
                bfr[ni] = *(const bf16x8*)&Bs[SWZ64(rr, kk * 4 + quad)];
            }
#pragma unroll
            for (int mi = 0; mi < 4; ++mi)
#pragma unroll
                for (int ni = 0; ni < 4; ++ni) {
                    if (SWAP)
                        acc[mi][ni] = __builtin_amdgcn_mfma_f32_16x16x32_bf16(
                            bfr[ni], af[mi], acc[mi][ni], 0, 0, 0);
                    else
                        acc[mi][ni] = __builtin_amdgcn_mfma_f32_16x16x32_bf16(
                            af[mi], bfr[ni], acc[mi][ni], 0, 0, 0);
                }
        }
        __syncthreads();
    }

    if (!SWAP) { // ---- V: direct transposed store (regs = 4 consecutive s)
#pragma unroll
        for (int mi = 0; mi < 4; ++mi)
#pragma unroll
            for (int ni = 0; ni < 4; ++ni) {
                int gm = m0 + wr + mi * 16 + quad * 4;
                int gn = n0 + wc + ni * 16 + mA;
                int d = gn & 1023, h = d >> 6, dk = d & 63;
                int b = gm >> 11, s = gm & 2047;
                ushort4 o;
                o.x = f2bf(acc[mi][ni][0]);
                o.y = f2bf(acc[mi][ni][1]);
                o.z = f2bf(acc[mi][ni][2]);
                o.w = f2bf(acc[mi][ni][3]);
                *(ushort4*)&Vt[((size_t)(b * NUM_HEADS + h) * DK + dk) * SEQ + s] = o;
            }
    } else { // ---- Q/K transposed acc: col = s (mA), regs = 4 consecutive dk
        unsigned short* Dst = (n0 >> 10) == 0 ? Qr : Kr; // block-uniform
#pragma unroll
        for (int mi = 0; mi < 4; ++mi) {
            int gm = m0 + wr + mi * 16 + mA;
            int b = gm >> 11, s = gm & 2047;
#pragma unroll
            for (int ni = 0; ni < 4; ++ni) {
                int gnb = n0 + wc + ni * 16 + quad * 4;
                int h = (gnb >> 6) & 15, dkb = gnb & 63;
                int f0 = dkb >> 1;
                float2 t0 = RT[f0 * SEQ + s];
                float2 t1 = RT[(f0 + 1) * SEQ + s];
                float a0 = acc[mi][ni][0], a1 = acc[mi][ni][1];
                float a2 = acc[mi][ni][2], a3 = acc[mi][ni][3];
                ushort4 o;
                o.x = f2bf(a0 * t0.x - a1 * t0.y);
                o.y = f2bf(a1 * t0.x + a0 * t0.y);
                o.z = f2bf(a2 * t1.x - a3 * t1.y);
                o.w = f2bf(a3 * t1.x + a2 * t1.y);
                *(ushort4*)&Dst[((size_t)(b * NUM_HEADS + h) * SEQ + s) * DK + dkb] = o;
            }
        }
    }
}

// ---------------- GEMM 128 x TN, BK=64: C = A * B^T (out-projection) -------
template <int TN, int OUT_BF16>
__global__ __launch_bounds__(256) void gemm_tile(
    const unsigned short* __restrict__ A, const unsigned short* __restrict__ B,
    void* __restrict__ Cout, int M, int N, int K) {
    __shared__ unsigned short As[128 * 64];
    __shared__ unsigned short Bs[TN * 64];
    const int m0 = blockIdx.y * 128, n0 = blockIdx.x * TN;
    const int t = threadIdx.x;
    const int lane = t & 63, wave = t >> 6;
    const int mA = lane & 15, quad = lane >> 4;
    constexpr int MI = (TN == 128) ? 4 : 2;
    constexpr int NI = 4;
    const int wr = (TN == 128) ? (wave >> 1) * 64 : wave * 32;
    const int wc = (TN == 128) ? (wave & 1) * 64 : 0;

    f32x4 acc[MI][NI] = {};
    for (int k0 = 0; k0 < K; k0 += 64) {
#pragma unroll
        for (int i = 0; i < 4; ++i) {
            int ch = i * 256 + t;
            int r = ch >> 3, b = (ch & 7) ^ (r & 7);
            async16(A + (size_t)(m0 + r) * K + k0 + b * 8, (char*)As + ch * 16);
        }
#pragma unroll
        for (int i = 0; i < TN / 32; ++i) {
            int ch = i * 256 + t;
            int r = ch >> 3, b = (ch & 7) ^ (r & 7);
            async16(B + (size_t)(n0 + r) * K + k0 + b * 8, (char*)Bs + ch * 16);
        }
        __syncthreads();
#pragma unroll
        for (int kk = 0; kk < 2; ++kk) {
            bf16x8 af[MI], bfr[NI];
#pragma unroll
            for (int mi = 0; mi < MI; ++mi) {
                int rr = wr + mi * 16 + mA;
                af[mi] = *(const bf16x8*)&As[SWZ64(rr, kk * 4 + quad)];
            }
#pragma unroll
            for (int ni = 0; ni < NI; ++ni) {
                int rr = wc + ni * 16 + mA;
                bfr[ni] = *(const bf16x8*)&Bs[SWZ64(rr, kk * 4 + quad)];
            }
#pragma unroll
            for (int mi = 0; mi < MI; ++mi)
#pragma unroll
                for (int ni = 0; ni < NI; ++ni)
                    acc[mi][ni] = __builtin_amdgcn_mfma_f32_16x16x32_bf16(
                        af[mi], bfr[ni], acc[mi][ni], 0, 0, 0);
        }
        __syncthreads();
    }
#pragma unroll
    for (int mi = 0; mi < MI; ++mi)
#pragma unroll
        for (int ni = 0; ni < NI; ++ni)
#pragma unroll
            for (int r = 0; r < 4; ++r) {
                int gm = m0 + wr + mi * 16 + quad * 4 + r;
                int gn = n0 + wc + ni * 16 + mA;
                if (OUT_BF16)
                    ((unsigned short*)Cout)[(size_t)gm * N + gn] = f2bf(acc[mi][ni][r]);
                else
                    ((float*)Cout)[(size_t)gm * N + gn] = acc[mi][ni][r];
            }
}

// ---------------- Flash attention v6 (known-good 43 us) ----------------
// 256 thr / 4 waves; block = 64 q rows of one (b,h). KV 64-tiles staged via
// global_load_lds shared by all 4 waves, double-buffered. LDS 40960 B ->
// 4 blocks/CU. Static-max softmax (offset cancels in P V / P 1).
__global__ __launch_bounds__(256, 4) void flash_attn6(
    const unsigned short* __restrict__ Qr, const unsigned short* __restrict__ Kr,
    const unsigned short* __restrict__ Vt, unsigned short* __restrict__ Att) {
    __shared__ unsigned short Ks[2][64 * 64]; // 16 KB (front reused for Lw)
    __shared__ unsigned short Vs[2][64 * 64]; // 16 KB
    __shared__ unsigned short Ps[4][16 * 64]; // 8 KB, XOR-swizzled rows
    const int bh = blockIdx.x;
    const int qt = 31 - (int)blockIdx.y; // LPT: longest first
    const int t = threadIdx.x;
    const int lane = t & 63, wave = t >> 6;
    const int mA = lane & 15, quad = lane >> 4;
    const int qr0 = qt * 64 + wave * 16;
    const size_t qkbase = (size_t)bh * SEQ * DK;
    const unsigned short* Kg = Kr + qkbase;
    const unsigned short* Vg = Vt + (size_t)bh * DK * SEQ;

    bf16x8 aq[2];
#pragma unroll
    for (int c = 0; c < 2; ++c) {
        bf16x8 raw = *(const bf16x8*)&Qr[qkbase + (size_t)(qr0 + mA) * DK + c * 32 + quad * 8];
        bf16x8 s;
#pragma unroll
        for (int j = 0; j < 8; ++j)
            s[j] = (short)f2bf(bf2f((unsigned short)raw[j]) * (0.125f * LOG2E));
        aq[c] = s;
    }

    f32x4 accT[4] = {};
    float lsum[4] = {};

#pragma unroll
    for (int i = 0; i < 2; ++i) {
        int ch = i * 256 + t;
        int row = ch >> 3, sb = (ch & 7) ^ (row & 7);
        async16(Kg + (size_t)row * DK + sb * 8, (char*)Ks[0] + ch * 16);
        async16(Vg + (size_t)row * SEQ + sb * 8, (char*)Vs[0] + ch * 16);
    }

    for (int jt = 0; jt <= qt; ++jt) {
        __syncthreads();
        const int cur = jt & 1;
        if (jt < qt) {
            const int j1 = (jt + 1) * 64;
#pragma unroll
            for (int i = 0; i < 2; ++i) {
                int ch = i * 256 + t;
                int row = ch >> 3, sb = (ch & 7) ^ (row & 7);
                async16(Kg + (size_t)(j1 + row) * DK + sb * 8, (char*)Ks[cur ^ 1] + ch * 16);
                async16(Vg + (size_t)row * SEQ + j1 + sb * 8, (char*)Vs[cur ^ 1] + ch * 16);
            }
        }
        const int j0 = jt * 64;
        const unsigned short* Kt = Ks[cur];
        const unsigned short* Vtile = Vs[cur];
        unsigned short* Pw = Ps[wave];

        f32x4 sc[4] = {};
#pragma unroll
        for (int js = 0; js < 4; ++js) {
            int row = js * 16 + mA;
            bf16x8 b0 = *(const bf16x8*)&Kt[SWZ64(row, quad)];
            bf16x8 b1 = *(const bf16x8*)&Kt[SWZ64(row, quad + 4)];
            sc[js] = __builtin_amdgcn_mfma_f32_16x16x32_bf16(aq[0], b0, sc[js], 0, 0, 0);
            sc[js] = __builtin_amdgcn_mfma_f32_16x16x32_bf16(aq[1], b1, sc[js], 0, 0, 0);
        }
        if (jt == qt) {
#pragma unroll
            for (int js = 0; js < 4; ++js) {
                int gcol = j0 + js * 16 + mA;
#pragma unroll
                for (int r = 0; r < 4; ++r)
                    if (gcol > qr0 + quad * 4 + r) sc[js][r] = -1e30f;
            }
        }

#pragma unroll
        for (int js = 0; js < 4; ++js)
#pragma unroll
            for (int r = 0; r < 4; ++r) {
                float p = __builtin_amdgcn_exp2f(sc[js][r] - FIXM);
                lsum[r] += p;
                int q = quad * 4 + r;
                Pw[SWZ64(q, js * 2 + (mA >> 3)) + (mA & 7)] = f2bf_trunc(p);
            }
        bf16x8 ap0 = *(const bf16x8*)&Pw[SWZ64(mA, quad)];
        bf16x8 ap1 = *(const bf16x8*)&Pw[SWZ64(mA, quad + 4)];
#pragma unroll
        for (int tn = 0; tn < 4; ++tn) {
            int row = tn * 16 + mA;
            bf16x8 bv0 = *(const bf16x8*)&Vtile[SWZ64(row, quad)];
            bf16x8 bv1 = *(const bf16x8*)&Vtile[SWZ64(row, quad + 4)];
            accT[tn] = __builtin_amdgcn_mfma_f32_16x16x32_bf16(bv0, ap0, accT[tn], 0, 0, 0);
            accT[tn] = __builtin_amdgcn_mfma_f32_16x16x32_bf16(bv1, ap1, accT[tn], 0, 0, 0);
        }
    }

#pragma unroll
    for (int r = 0; r < 4; ++r)
#pragma unroll
        for (int off = 1; off < 16; off <<= 1)
            lsum[r] += __shfl_xor(lsum[r], off, 64);
    __syncthreads();
    float* LL = (float*)Ks;
    if (mA == 0)
#pragma unroll
        for (int r = 0; r < 4; ++r) LL[wave * 16 + quad * 4 + r] = lsum[r];
    __syncthreads();
    const float rl = 1.0f / LL[wave * 16 + mA];

    const int b = bh >> 4, h = bh & 15;
#pragma unroll
    for (int tn = 0; tn < 4; ++tn) {
        ushort4 o;
        o.x = f2bf(accT[tn][0] * rl);
        o.y = f2bf(accT[tn][1] * rl);
        o.z = f2bf(accT[tn][2] * rl);
        o.w = f2bf(accT[tn][3] * rl);
        *(ushort4*)&Att[(size_t)(b * SEQ + qr0 + mA) * D_MODEL + h * DK + tn * 16 + quad * 4] = o;
    }
}

extern "C" void kernel_launch(void* const* d_in, const int* in_sizes, int n_in,
                              void* d_out, int out_size, void* d_ws, size_t ws_size,
                              hipStream_t stream) {
    const float* X = (const float*)d_in[0];
    const float* Wq = (const float*)d_in[1];
    const float* Wk = (const float*)d_in[2];
    const float* Wv = (const float*)d_in[3];
    const float* Wo = (const float*)d_in[4];

    char* ws = (char*)d_ws;
    // layout (MiB): Xb 0-8 | Wqkvb 8-14 | Wob 14-16 | Qr 16-24 | Kr 24-32 |
    //               Vt 32-40 | Att 40-48 | RT 48-48.5
    unsigned short* Xb    = (unsigned short*)(ws + 0);
    unsigned short* Wqkvb = (unsigned short*)(ws + (8u << 20));
    unsigned short* Wob   = (unsigned short*)(ws + (14u << 20));
    unsigned short* Qr    = (unsigned short*)(ws + (16u << 20));
    unsigned short* Kr    = (unsigned short*)(ws + (24u << 20));
    unsigned short* Vt    = (unsigned short*)(ws + (32u << 20));
    unsigned short* Att   = (unsigned short*)(ws + (40u << 20));
    float2*         RT    = (float2*)(ws + (48u << 20));

    cast_all<<<8192 + 64, 256, 0, stream>>>((const float4*)X, (const float4*)Wq,
                                            (const float4*)Wk, (const float4*)Wv,
                                            (const float4*)Wo, (ushort4*)Xb,
                                            (ushort4*)Wqkvb, (ushort4*)Wob, RT);

    // fused QKV projection: Q/K sections (swapped MFMA + rope), then V section
    gemm_qkv<1><<<dim3(16, MROWS / 128), 256, 0, stream>>>(
        Xb, Wqkvb, RT, Qr, Kr, Vt, 0);
    gemm_qkv<0><<<dim3(8, MROWS / 128), 256, 0, stream>>>(
        Xb, Wqkvb, RT, Qr, Kr, Vt, 2048);

    flash_attn6<<<dim3(BATCH * NUM_HEADS, 32), 256, 0, stream>>>(Qr, Kr, Vt, Att);

    // output projection (fp32 out), 128x64 tiles for 2 blocks/CU
    gemm_tile<64, 0><<<dim3(D_MODEL / 64, MROWS / 128), 256, 0, stream>>>(
        Att, Wob, d_out, MROWS, D_MODEL, D_MODEL);
}

// Round 11
// 185.245 us; speedup vs baseline: 1.1133x; 1.0170x over previous
//
#include <hip/hip_runtime.h>
#include <stdint.h>

#define D_MODEL 1024
#define NUM_HEADS 16
#define DK 64
#define SEQ 2048
#define BATCH 2
#define MROWS (BATCH * SEQ) /* 4096 */
#define LOG2E 1.4426950408889634f
#define FIXM 14.0f /* static softmax max, base-2 domain */

typedef short bf16x8 __attribute__((ext_vector_type(8)));
typedef float f32x4 __attribute__((ext_vector_type(4)));

__device__ __forceinline__ unsigned short f2bf(float f) { // RNE
    unsigned int u = __float_as_uint(f);
    u = (u + 0x7fffu + ((u >> 16) & 1u)) >> 16;
    return (unsigned short)u;
}
__device__ __forceinline__ unsigned short f2bf_trunc(float f) { // 1-op, P only
    return (unsigned short)(__float_as_uint(f) >> 16);
}
__device__ __forceinline__ float bf2f(unsigned short h) {
    return __uint_as_float(((unsigned int)h) << 16);
}
__device__ __forceinline__ void async16(const void* g, void* l) {
    __builtin_amdgcn_global_load_lds(
        (const __attribute__((address_space(1))) void*)g,
        (__attribute__((address_space(3))) void*)l, 16, 0, 0);
}
// 64-col bf16 tile: 8 16B-chunks/row; phys chunk p of row r holds logical p^(r&7)
#define SWZ64(row, b) ((((row) * 8) + ((b) ^ ((row) & 7))) * 8)
// 128-col bf16 tile: 16 chunks/row, same 8-period XOR
#define SWZ128(row, b) ((((row) * 16) + ((b) ^ ((row) & 7))) * 8)

// ------------- merged cast fp32->bf16 + RoPE table fill -------------
__global__ void cast_all(const float4* __restrict__ X, const float4* __restrict__ Wq,
                         const float4* __restrict__ Wk, const float4* __restrict__ Wv,
                         const float4* __restrict__ Wo, ushort4* __restrict__ Xb,
                         ushort4* __restrict__ Wqkvb, ushort4* __restrict__ Wob,
                         float2* __restrict__ RT) {
    const int bx = blockIdx.x, t = threadIdx.x;
    if (bx < 8192) {
        int i = bx * 256 + t;
        const float4* src;
        ushort4* dst;
        int off;
        if (i < 1048576) { src = X; dst = Xb; off = i; }
        else if (i < 1310720) { src = Wq; dst = Wqkvb; off = i - 1048576; }
        else if (i < 1572864) { src = Wk; dst = Wqkvb + 262144; off = i - 1310720; }
        else if (i < 1835008) { src = Wv; dst = Wqkvb + 524288; off = i - 1572864; }
        else { src = Wo; dst = Wob; off = i - 1835008; }
        float4 v = src[off];
        ushort4 o;
        o.x = f2bf(v.x); o.y = f2bf(v.y); o.z = f2bf(v.z); o.w = f2bf(v.w);
        dst[off] = o;
    } else { // rope table: 16384 threads x 4 s-entries
        int idx = (bx - 8192) * 256 + t;
        int f = idx >> 9;
        int s4 = (idx & 511) * 4;
        float invf = __expf(-(float)(2 * f) * (9.210340371976184f / 64.0f));
#pragma unroll
        for (int j = 0; j < 4; ++j) {
            int s = s4 + j;
            float sn, cs;
            __sincosf((float)s * invf, &sn, &cs);
            RT[f * SEQ + s] = make_float2(cs, sn);
        }
    }
}

// -------- Fused QKV GEMM 128x128 BK=64, one launch, top-level branch --------
// Grid (24, 32). bx<16: Q/K sections (swapped-operand MFMA -> D=C^T, rope via
// RT table, stores [bh][s][dk]). bx>=16: V section (normal MFMA, transposed
// store to Vt [bh][d][s]). TWO complete straight-line K-loops - no branch
// inside either loop body (round-9 lesson).
__global__ __launch_bounds__(256) void gemm_qkv(
    const unsigned short* __restrict__ A, const unsigned short* __restrict__ B,
    const float2* __restrict__ RT, unsigned short* __restrict__ Qr,
    unsigned short* __restrict__ Kr, unsigned short* __restrict__ Vt) {
    __shared__ unsigned short As[128 * 64];
    __shared__ unsigned short Bs[128 * 64];
    const int K = D_MODEL;
    const int bx = blockIdx.x;
    const int m0 = blockIdx.y * 128;
    const int t = threadIdx.x;
    const int lane = t & 63, wave = t >> 6;
    const int mA = lane & 15, quad = lane >> 4;
    const int wr = (wave >> 1) * 64, wc = (wave & 1) * 64;

    if (bx < 16) { // ================= Q/K body =================
        const int n0 = bx * 128;
        f32x4 acc[4][4] = {};
        for (int k0 = 0; k0 < K; k0 += 64) {
#pragma unroll
            for (int i = 0; i < 4; ++i) {
                int ch = i * 256 + t;
                int r = ch >> 3, b = (ch & 7) ^ (r & 7);
                async16(A + (size_t)(m0 + r) * K + k0 + b * 8, (char*)As + ch * 16);
                async16(B + (size_t)(n0 + r) * K + k0 + b * 8, (char*)Bs + ch * 16);
            }
            __syncthreads();
#pragma unroll
            for (int kk = 0; kk < 2; ++kk) {
                bf16x8 af[4], bfr[4];
#pragma unroll
                for (int mi = 0; mi < 4; ++mi) {
                    int rr = wr + mi * 16 + mA;
                    af[mi] = *(const bf16x8*)&As[SWZ64(rr, kk * 4 + quad)];
                }
#pragma unroll
                for (int ni = 0; ni < 4; ++ni) {
                    int rr = wc + ni * 16 + mA;
                    bfr[ni] = *(const bf16x8*)&Bs[SWZ64(rr, kk * 4 + quad)];
                }
#pragma unroll
                for (int mi = 0; mi < 4; ++mi)
#pragma unroll
                    for (int ni = 0; ni < 4; ++ni)
                        acc[mi][ni] = __builtin_amdgcn_mfma_f32_16x16x32_bf16(
                            bfr[ni], af[mi], acc[mi][ni], 0, 0, 0); // swapped
            }
            __syncthreads();
        }
        unsigned short* Dst = (n0 < 1024) ? Qr : Kr; // block-uniform
#pragma unroll
        for (int mi = 0; mi < 4; ++mi) {
            int gm = m0 + wr + mi * 16 + mA;
            int b = gm >> 11, s = gm & 2047;
#pragma unroll
            for (int ni = 0; ni < 4; ++ni) {
                int gnb = n0 + wc + ni * 16 + quad * 4;
                int h = (gnb >> 6) & 15, dkb = gnb & 63;
                int f0 = dkb >> 1;
                float2 t0 = RT[f0 * SEQ + s];
                float2 t1 = RT[(f0 + 1) * SEQ + s];
                float a0 = acc[mi][ni][0], a1 = acc[mi][ni][1];
                float a2 = acc[mi][ni][2], a3 = acc[mi][ni][3];
                ushort4 o;
                o.x = f2bf(a0 * t0.x - a1 * t0.y);
                o.y = f2bf(a1 * t0.x + a0 * t0.y);
                o.z = f2bf(a2 * t1.x - a3 * t1.y);
                o.w = f2bf(a3 * t1.x + a2 * t1.y);
                *(ushort4*)&Dst[((size_t)(b * NUM_HEADS + h) * SEQ + s) * DK + dkb] = o;
            }
        }
    } else { // ================= V body =================
        const int n0 = 2048 + (bx - 16) * 128;
        f32x4 acc[4][4] = {};
        for (int k0 = 0; k0 < K; k0 += 64) {
#pragma unroll
            for (int i = 0; i < 4; ++i) {
                int ch = i * 256 + t;
                int r = ch >> 3, b = (ch & 7) ^ (r & 7);
                async16(A + (size_t)(m0 + r) * K + k0 + b * 8, (char*)As + ch * 16);
                async16(B + (size_t)(n0 + r) * K + k0 + b * 8, (char*)Bs + ch * 16);
            }
            __syncthreads();
#pragma unroll
            for (int kk = 0; kk < 2; ++kk) {
                bf16x8 af[4], bfr[4];
#pragma unroll
                for (int mi = 0; mi < 4; ++mi) {
                    int rr = wr + mi * 16 + mA;
                    af[mi] = *(const bf16x8*)&As[SWZ64(rr, kk * 4 + quad)];
                }
#pragma unroll
                for (int ni = 0; ni < 4; ++ni) {
                    int rr = wc + ni * 16 + mA;
                    bfr[ni] = *(const bf16x8*)&Bs[SWZ64(rr, kk * 4 + quad)];
                }
#pragma unroll
                for (int mi = 0; mi < 4; ++mi)
#pragma unroll
                    for (int ni = 0; ni < 4; ++ni)
                        acc[mi][ni] = __builtin_amdgcn_mfma_f32_16x16x32_bf16(
                            af[mi], bfr[ni], acc[mi][ni], 0, 0, 0);
            }
            __syncthreads();
        }
#pragma unroll
        for (int mi = 0; mi < 4; ++mi)
#pragma unroll
            for (int ni = 0; ni < 4; ++ni) {
                int gm = m0 + wr + mi * 16 + quad * 4;
                int gn = n0 + wc + ni * 16 + mA;
                int d = gn & 1023, h = d >> 6, dk = d & 63;
                int b = gm >> 11, s = gm & 2047;
                ushort4 o;
                o.x = f2bf(acc[mi][ni][0]);
                o.y = f2bf(acc[mi][ni][1]);
                o.z = f2bf(acc[mi][ni][2]);
                o.w = f2bf(acc[mi][ni][3]);
                *(ushort4*)&Vt[((size_t)(b * NUM_HEADS + h) * DK + dk) * SEQ + s] = o;
            }
    }
}

// ---------------- Out-projection GEMM 128x64, BK=128 ----------------
// 8 K-steps (half the barrier drains of BK=64). LDS 48 KB; grid 512 = 2/CU.
__global__ __launch_bounds__(256) void gemm_out(
    const unsigned short* __restrict__ A, const unsigned short* __restrict__ B,
    float* __restrict__ Cout, int M, int N, int K) {
    __shared__ unsigned short As[128 * 128]; // 32 KB
    __shared__ unsigned short Bs[64 * 128];  // 16 KB
    const int m0 = blockIdx.y * 128, n0 = blockIdx.x * 64;
    const int t = threadIdx.x;
    const int lane = t & 63, wave = t >> 6;
    const int mA = lane & 15, quad = lane >> 4;
    const int wr = wave * 32;

    f32x4 acc[2][4] = {};
    for (int k0 = 0; k0 < K; k0 += 128) {
#pragma unroll
        for (int i = 0; i < 8; ++i) { // A: 2048 chunks of 16B
            int ch = i * 256 + t;
            int r = ch >> 4, bl = ch & 15;
            int b = bl ^ (r & 7);
            async16(A + (size_t)(m0 + r) * K + k0 + b * 8, (char*)As + ch * 16);
        }
#pragma unroll
        for (int i = 0; i < 4; ++i) { // B: 1024 chunks
            int ch = i * 256 + t;
            int r = ch >> 4, bl = ch & 15;
            int b = bl ^ (r & 7);
            async16(B + (size_t)(n0 + r) * K + k0 + b * 8, (char*)Bs + ch * 16);
        }
        __syncthreads();
#pragma unroll
        for (int kk = 0; kk < 4; ++kk) {
            bf16x8 af[2], bfr[4];
#pragma unroll
            for (int mi = 0; mi < 2; ++mi) {
                int rr = wr + mi * 16 + mA;
                af[mi] = *(const bf16x8*)&As[SWZ128(rr, kk * 4 + quad)];
            }
#pragma unroll
            for (int ni = 0; ni < 4; ++ni) {
                int rr = ni * 16 + mA;
                bfr[ni] = *(const bf16x8*)&Bs[SWZ128(rr, kk * 4 + quad)];
            }
#pragma unroll
            for (int mi = 0; mi < 2; ++mi)
#pragma unroll
                for (int ni = 0; ni < 4; ++ni)
                    acc[mi][ni] = __builtin_amdgcn_mfma_f32_16x16x32_bf16(
                        af[mi], bfr[ni], acc[mi][ni], 0, 0, 0);
        }
        __syncthreads();
    }
#pragma unroll
    for (int mi = 0; mi < 2; ++mi)
#pragma unroll
        for (int ni = 0; ni < 4; ++ni)
#pragma unroll
            for (int r = 0; r < 4; ++r) {
                int gm = m0 + wr + mi * 16 + quad * 4 + r;
                int gn = n0 + ni * 16 + mA;
                Cout[(size_t)gm * N + gn] = acc[mi][ni][r];
            }
}

// ---------------- Flash attention v6 (known-good) ----------------
__global__ __launch_bounds__(256, 4) void flash_attn6(
    const unsigned short* __restrict__ Qr, const unsigned short* __restrict__ Kr,
    const unsigned short* __restrict__ Vt, unsigned short* __restrict__ Att) {
    __shared__ unsigned short Ks[2][64 * 64];
    __shared__ unsigned short Vs[2][64 * 64];
    __shared__ unsigned short Ps[4][16 * 64];
    const int bh = blockIdx.x;
    const int qt = 31 - (int)blockIdx.y; // LPT
    const int t = threadIdx.x;
    const int lane = t & 63, wave = t >> 6;
    const int mA = lane & 15, quad = lane >> 4;
    const int qr0 = qt * 64 + wave * 16;
    const size_t qkbase = (size_t)bh * SEQ * DK;
    const unsigned short* Kg = Kr + qkbase;
    const unsigned short* Vg = Vt + (size_t)bh * DK * SEQ;

    bf16x8 aq[2];
#pragma unroll
    for (int c = 0; c < 2; ++c) {
        bf16x8 raw = *(const bf16x8*)&Qr[qkbase + (size_t)(qr0 + mA) * DK + c * 32 + quad * 8];
        bf16x8 s;
#pragma unroll
        for (int j = 0; j < 8; ++j)
            s[j] = (short)f2bf(bf2f((unsigned short)raw[j]) * (0.125f * LOG2E));
        aq[c] = s;
    }

    f32x4 accT[4] = {};
    float lsum[4] = {};

#pragma unroll
    for (int i = 0; i < 2; ++i) {
        int ch = i * 256 + t;
        int row = ch >> 3, sb = (ch & 7) ^ (row & 7);
        async16(Kg + (size_t)row * DK + sb * 8, (char*)Ks[0] + ch * 16);
        async16(Vg + (size_t)row * SEQ + sb * 8, (char*)Vs[0] + ch * 16);
    }

    for (int jt = 0; jt <= qt; ++jt) {
        __syncthreads();
        const int cur = jt & 1;
        if (jt < qt) {
            const int j1 = (jt + 1) * 64;
#pragma unroll
            for (int i = 0; i < 2; ++i) {
                int ch = i * 256 + t;
                int row = ch >> 3, sb = (ch & 7) ^ (row & 7);
                async16(Kg + (size_t)(j1 + row) * DK + sb * 8, (char*)Ks[cur ^ 1] + ch * 16);
                async16(Vg + (size_t)row * SEQ + j1 + sb * 8, (char*)Vs[cur ^ 1] + ch * 16);
            }
        }
        const int j0 = jt * 64;
        const unsigned short* Kt = Ks[cur];
        const unsigned short* Vtile = Vs[cur];
        unsigned short* Pw = Ps[wave];

        f32x4 sc[4] = {};
#pragma unroll
        for (int js = 0; js < 4; ++js) {
            int row = js * 16 + mA;
            bf16x8 b0 = *(const bf16x8*)&Kt[SWZ64(row, quad)];
            bf16x8 b1 = *(const bf16x8*)&Kt[SWZ64(row, quad + 4)];
            sc[js] = __builtin_amdgcn_mfma_f32_16x16x32_bf16(aq[0], b0, sc[js], 0, 0, 0);
            sc[js] = __builtin_amdgcn_mfma_f32_16x16x32_bf16(aq[1], b1, sc[js], 0, 0, 0);
        }
        if (jt == qt) {
#pragma unroll
            for (int js = 0; js < 4; ++js) {
                int gcol = j0 + js * 16 + mA;
#pragma unroll
                for (int r = 0; r < 4; ++r)
                    if (gcol > qr0 + quad * 4 + r) sc[js][r] = -1e30f;
            }
        }

#pragma unroll
        for (int js = 0; js < 4; ++js)
#pragma unroll
            for (int r = 0; r < 4; ++r) {
                float p = __builtin_amdgcn_exp2f(sc[js][r] - FIXM);
                lsum[r] += p;
                int q = quad * 4 + r;
                Pw[SWZ64(q, js * 2 + (mA >> 3)) + (mA & 7)] = f2bf_trunc(p);
            }
        bf16x8 ap0 = *(const bf16x8*)&Pw[SWZ64(mA, quad)];
        bf16x8 ap1 = *(const bf16x8*)&Pw[SWZ64(mA, quad + 4)];
#pragma unroll
        for (int tn = 0; tn < 4; ++tn) {
            int row = tn * 16 + mA;
            bf16x8 bv0 = *(const bf16x8*)&Vtile[SWZ64(row, quad)];
            bf16x8 bv1 = *(const bf16x8*)&Vtile[SWZ64(row, quad + 4)];
            accT[tn] = __builtin_amdgcn_mfma_f32_16x16x32_bf16(bv0, ap0, accT[tn], 0, 0, 0);
            accT[tn] = __builtin_amdgcn_mfma_f32_16x16x32_bf16(bv1, ap1, accT[tn], 0, 0, 0);
        }
    }

#pragma unroll
    for (int r = 0; r < 4; ++r)
#pragma unroll
        for (int off = 1; off < 16; off <<= 1)
            lsum[r] += __shfl_xor(lsum[r], off, 64);
    __syncthreads();
    float* LL = (float*)Ks;
    if (mA == 0)
#pragma unroll
        for (int r = 0; r < 4; ++r) LL[wave * 16 + quad * 4 + r] = lsum[r];
    __syncthreads();
    const float rl = 1.0f / LL[wave * 16 + mA];

    const int b = bh >> 4, h = bh & 15;
#pragma unroll
    for (int tn = 0; tn < 4; ++tn) {
        ushort4 o;
        o.x = f2bf(accT[tn][0] * rl);
        o.y = f2bf(accT[tn][1] * rl);
        o.z = f2bf(accT[tn][2] * rl);
        o.w = f2bf(accT[tn][3] * rl);
        *(ushort4*)&Att[(size_t)(b * SEQ + qr0 + mA) * D_MODEL + h * DK + tn * 16 + quad * 4] = o;
    }
}

extern "C" void kernel_launch(void* const* d_in, const int* in_sizes, int n_in,
                              void* d_out, int out_size, void* d_ws, size_t ws_size,
                              hipStream_t stream) {
    const float* X = (const float*)d_in[0];
    const float* Wq = (const float*)d_in[1];
    const float* Wk = (const float*)d_in[2];
    const float* Wv = (const float*)d_in[3];
    const float* Wo = (const float*)d_in[4];

    char* ws = (char*)d_ws;
    // layout (MiB): Xb 0-8 | Wqkvb 8-14 | Wob 14-16 | Qr 16-24 | Kr 24-32 |
    //               Vt 32-40 | Att 40-48 | RT 48-48.5
    unsigned short* Xb    = (unsigned short*)(ws + 0);
    unsigned short* Wqkvb = (unsigned short*)(ws + (8u << 20));
    unsigned short* Wob   = (unsigned short*)(ws + (14u << 20));
    unsigned short* Qr    = (unsigned short*)(ws + (16u << 20));
    unsigned short* Kr    = (unsigned short*)(ws + (24u << 20));
    unsigned short* Vt    = (unsigned short*)(ws + (32u << 20));
    unsigned short* Att   = (unsigned short*)(ws + (40u << 20));
    float2*         RT    = (float2*)(ws + (48u << 20));

    cast_all<<<8192 + 64, 256, 0, stream>>>((const float4*)X, (const float4*)Wq,
                                            (const float4*)Wk, (const float4*)Wv,
                                            (const float4*)Wo, (ushort4*)Xb,
                                            (ushort4*)Wqkvb, (ushort4*)Wob, RT);

    // fused QKV projection + RoPE + V-transpose, ONE launch (768 blocks)
    gemm_qkv<<<dim3(24, MROWS / 128), 256, 0, stream>>>(
        Xb, Wqkvb, RT, Qr, Kr, Vt);

    flash_attn6<<<dim3(BATCH * NUM_HEADS, 32), 256, 0, stream>>>(Qr, Kr, Vt, Att);

    // output projection (fp32 out), BK=128: 8 K-steps
    gemm_out<<<dim3(D_MODEL / 64, MROWS / 128), 256, 0, stream>>>(
        Att, Wob, (float*)d_out, MROWS, D_MODEL, D_MODEL);
}